// Round 7
// baseline (284.876 us; speedup 1.0000x reference)
//
#include <hip/hip_runtime.h>

#define BB 4
#define LL 1024
#define CC 768
#define HH 12
#define DD 64

typedef unsigned short ushort_t;
typedef __attribute__((ext_vector_type(8))) short bf16x8;
typedef __attribute__((ext_vector_type(4))) float f32x4;
typedef __attribute__((ext_vector_type(2))) float f32x2;

__device__ inline ushort_t f2bf(float x) {
    union { float f; unsigned u; } v; v.f = x;
    unsigned r = (v.u + 0x7FFFu + ((v.u >> 16) & 1u)) >> 16;
    return (ushort_t)r;
}
__device__ inline float bf2f(ushort_t u) {
    union { unsigned u; float f; } v; v.u = ((unsigned)u) << 16;
    return v.f;
}
__device__ inline float u2f(unsigned u) {
    union { unsigned u; float f; } v; v.u = u;
    return v.f;
}

// Stage rows x 32 shorts from g (row stride `stride` shorts) into LDS,
// contiguous 64B rows, via async global->LDS (16B/lane, wave-uniform LDS base).
__device__ inline void stage_rows(const ushort_t* __restrict__ g, int stride,
                                  ushort_t* lds, int nbytes, int wave, int lane) {
    const int ko = (lane & 3) << 3;
    const int rsub = lane >> 2;
    for (int off = wave * 1024; off < nbytes; off += 4096) {
        int row = (off >> 6) + rsub;
        __builtin_amdgcn_global_load_lds(
            (const __attribute__((address_space(1))) void*)(g + (size_t)row * stride + ko),
            (__attribute__((address_space(3))) void*)(lds + (off >> 1)),
            16, 0, 0);
    }
}

// ---------------- prep: cast inputs + cast/transpose weights (one launch) ----------------
__global__ __launch_bounds__(256) void prep(const float* __restrict__ q, const float* __restrict__ kv,
                                            const float* __restrict__ w0, const float* __restrict__ w1,
                                            const float* __restrict__ w2, const float* __restrict__ w3,
                                            ushort_t* __restrict__ qo, ushort_t* __restrict__ kvo,
                                            ushort_t* __restrict__ o0, ushort_t* __restrict__ o1,
                                            ushort_t* __restrict__ o2, ushort_t* __restrict__ o3) {
    __shared__ float t[32][33];
    const int bx = blockIdx.x;
    if (bx < 3072) {
        const float* src = bx < 1536 ? q : kv;
        ushort_t* dst = bx < 1536 ? qo : kvo;
        int bb = bx < 1536 ? bx : bx - 1536;
        size_t i = ((size_t)bb * 256 + threadIdx.x) * 8;
        float4 a = *(const float4*)(src + i);
        float4 b = *(const float4*)(src + i + 4);
        ushort_t u[8] = {f2bf(a.x), f2bf(a.y), f2bf(a.z), f2bf(a.w),
                         f2bf(b.x), f2bf(b.y), f2bf(b.z), f2bf(b.w)};
        *(uint4*)(dst + i) = *(uint4*)u;
    } else {
        int w = bx - 3072;
        int z = w / 576, rem = w % 576;
        const float* W = z == 0 ? w0 : z == 1 ? w1 : z == 2 ? w2 : w3;
        ushort_t* Wt   = z == 0 ? o0 : z == 1 ? o1 : z == 2 ? o2 : o3;
        const int c = threadIdx.x & 31, r0 = threadIdx.x >> 5;
        const int kb = (rem / 24) * 32, nb = (rem % 24) * 32;
#pragma unroll
        for (int i = 0; i < 4; ++i)
            t[r0 + 8 * i][c] = W[(size_t)(kb + r0 + 8 * i) * CC + nb + c];
        __syncthreads();
#pragma unroll
        for (int i = 0; i < 4; ++i)
            Wt[(size_t)(nb + r0 + 8 * i) * CC + kb + c] = f2bf(t[c][r0 + 8 * i]);
    }
}

// ---------------- fused Q/K/V projection (MFMA bf16), z picks target ----------------
__global__ __launch_bounds__(256) void proj_gemm(const ushort_t* __restrict__ Aq,
                                                 const ushort_t* __restrict__ Akv,
                                                 const ushort_t* __restrict__ Wqt,
                                                 const ushort_t* __restrict__ Wkt,
                                                 const ushort_t* __restrict__ Wvt,
                                                 ushort_t* __restrict__ Qo,
                                                 ushort_t* __restrict__ Ko,
                                                 ushort_t* __restrict__ Vto) {
    const int z = blockIdx.z;
    const ushort_t* A  = (z == 0) ? Aq : Akv;
    const ushort_t* Wt = (z == 0) ? Wqt : (z == 1 ? Wkt : Wvt);

    __shared__ __align__(16) ushort_t a_lds[128 * 32];
    __shared__ __align__(16) ushort_t b_lds[128 * 32];

    const int tid = threadIdx.x;
    const int bm = blockIdx.x * 128, bn = blockIdx.y * 128;
    const int wave = tid >> 6, lane = tid & 63;
    const int quad = lane >> 4, lq = lane & 15;
    const int wr = wave >> 1, wc = wave & 1;

    f32x4 acc[4][4] = {};

    for (int k0 = 0; k0 < CC; k0 += 32) {
        stage_rows(A + (size_t)bm * CC + k0, CC, a_lds, 8192, wave, lane);
        stage_rows(Wt + (size_t)bn * CC + k0, CC, b_lds, 8192, wave, lane);
        __syncthreads();
        bf16x8 af[4], bfr[4];
#pragma unroll
        for (int mi = 0; mi < 4; ++mi)
            af[mi] = *(bf16x8*)&a_lds[(wr * 64 + mi * 16 + lq) * 32 + quad * 8];
#pragma unroll
        for (int ni = 0; ni < 4; ++ni)
            bfr[ni] = *(bf16x8*)&b_lds[(wc * 64 + ni * 16 + lq) * 32 + quad * 8];
#pragma unroll
        for (int mi = 0; mi < 4; ++mi)
#pragma unroll
            for (int ni = 0; ni < 4; ++ni)
                acc[mi][ni] = __builtin_amdgcn_mfma_f32_16x16x32_bf16(af[mi], bfr[ni], acc[mi][ni], 0, 0, 0);
        __syncthreads();
    }

    const float scale = (z == 0) ? 0.125f : 1.0f;
#pragma unroll
    for (int mi = 0; mi < 4; ++mi)
#pragma unroll
        for (int ni = 0; ni < 4; ++ni)
#pragma unroll
            for (int r = 0; r < 4; ++r) {
                int row = bm + wr * 64 + mi * 16 + quad * 4 + r;  // b*1024+l
                int col = bn + wc * 64 + ni * 16 + lq;            // h*64+d
                int b = row >> 10, l = row & 1023, h = col >> 6, d = col & 63;
                ushort_t v = f2bf(acc[mi][ni][r] * scale);
                if (z == 0)      Qo[((size_t)(b * HH + h) * LL + l) * DD + d] = v;
                else if (z == 1) Ko[((size_t)(b * HH + h) * LL + l) * DD + d] = v;
                else             Vto[((size_t)(b * HH + h) * DD + d) * LL + l] = v;
            }
}

// ---------------- qk_premix: S'[b,i,l,k] = premix(QK^T), plus z[b,i,l] = sum_k exp(S') ----------------
// Block: (k-tile 32, l-tile 64, b). h-loop builds T[12][64][32] in LDS (fp32->bf16),
// then premix in-LDS, write S' bf16 + atomic z partial sums.
__global__ __launch_bounds__(256) void qk_premix(const ushort_t* __restrict__ Q,
                                                 const ushort_t* __restrict__ K,
                                                 const float* __restrict__ Wpre,
                                                 ushort_t* __restrict__ S,
                                                 float* __restrict__ z) {
    __shared__ __align__(16) ushort_t qt[2][128 * 32];  // [dhalf*64+l][32]
    __shared__ __align__(16) ushort_t kt[2][64 * 32];   // [dhalf*32+k][32]
    __shared__ __align__(16) ushort_t T[HH * 64 * 32];  // [h][l][k] 48 KB

    const int tid = threadIdx.x;
    const int k0 = blockIdx.x * 32, l0 = blockIdx.y * 64, b = blockIdx.z;
    const int wave = tid >> 6, lane = tid & 63;
    const int quad = lane >> 4, lq = lane & 15;

    // prefetch h=0
    {
        const ushort_t* Qh = Q + ((size_t)(b * HH) * LL + l0) * DD;
        const ushort_t* Kh = K + ((size_t)(b * HH) * LL + k0) * DD;
        stage_rows(Qh,      DD, qt[0],        4096, wave, lane);
        stage_rows(Qh + 32, DD, qt[0] + 2048, 4096, wave, lane);
        stage_rows(Kh,      DD, kt[0],        2048, wave, lane);
        stage_rows(Kh + 32, DD, kt[0] + 1024, 2048, wave, lane);
    }

    for (int h = 0; h < HH; ++h) {
        const int cur = h & 1, nxt = cur ^ 1;
        __syncthreads();   // dma(h) complete; reads of buf nxt (from h-1) done
        if (h + 1 < HH) {
            const ushort_t* Qh = Q + ((size_t)(b * HH + h + 1) * LL + l0) * DD;
            const ushort_t* Kh = K + ((size_t)(b * HH + h + 1) * LL + k0) * DD;
            stage_rows(Qh,      DD, qt[nxt],        4096, wave, lane);
            stage_rows(Qh + 32, DD, qt[nxt] + 2048, 4096, wave, lane);
            stage_rows(Kh,      DD, kt[nxt],        2048, wave, lane);
            stage_rows(Kh + 32, DD, kt[nxt] + 1024, 2048, wave, lane);
        }
        f32x4 acc[2] = {};
#pragma unroll
        for (int ks = 0; ks < 2; ++ks) {
            bf16x8 af = *(bf16x8*)&qt[cur][(ks * 64 + wave * 16 + lq) * 32 + quad * 8];
#pragma unroll
            for (int nt = 0; nt < 2; ++nt) {
                bf16x8 bf = *(bf16x8*)&kt[cur][(ks * 32 + nt * 16 + lq) * 32 + quad * 8];
                acc[nt] = __builtin_amdgcn_mfma_f32_16x16x32_bf16(af, bf, acc[nt], 0, 0, 0);
            }
        }
#pragma unroll
        for (int nt = 0; nt < 2; ++nt)
#pragma unroll
            for (int r = 0; r < 4; ++r) {
                int l = wave * 16 + quad * 4 + r;
                T[(h * 64 + l) * 32 + nt * 16 + lq] = f2bf(acc[nt][r]);
            }
    }
    __syncthreads();

    // premix: thread owns (l = tid>>2, k8 = (tid&3)*8), 8 k-elems, all 12 i.
    const int l = tid >> 2, k8 = (tid & 3) * 8;
    f32x2 pa[HH][4];
#pragma unroll
    for (int i = 0; i < HH; ++i) { pa[i][0] = 0.f; pa[i][1] = 0.f; pa[i][2] = 0.f; pa[i][3] = 0.f; }
#pragma unroll
    for (int h = 0; h < HH; ++h) {
        uint4 raw = *(uint4*)&T[(h * 64 + l) * 32 + k8];
        f32x2 v[4];
        v[0].x = u2f(raw.x << 16); v[0].y = u2f(raw.x & 0xFFFF0000u);
        v[1].x = u2f(raw.y << 16); v[1].y = u2f(raw.y & 0xFFFF0000u);
        v[2].x = u2f(raw.z << 16); v[2].y = u2f(raw.z & 0xFFFF0000u);
        v[3].x = u2f(raw.w << 16); v[3].y = u2f(raw.w & 0xFFFF0000u);
#pragma unroll
        for (int i = 0; i < HH; ++i) {
            float w = Wpre[h * HH + i];   // uniform -> s_load
            pa[i][0] += v[0] * w; pa[i][1] += v[1] * w;
            pa[i][2] += v[2] * w; pa[i][3] += v[3] * w;
        }
    }

    float zs[HH];
#pragma unroll
    for (int i = 0; i < HH; ++i) {
        ushort_t u[8];
        float e = 0.f;
#pragma unroll
        for (int j = 0; j < 4; ++j) {
            u[2 * j]     = f2bf(pa[i][j].x);
            u[2 * j + 1] = f2bf(pa[i][j].y);
            e += __expf(bf2f(u[2 * j])) + __expf(bf2f(u[2 * j + 1]));
        }
        zs[i] = e;
        *(uint4*)&S[((size_t)(b * HH + i) * LL + l0 + l) * LL + k0 + k8] = *(uint4*)u;
    }
    // reduce zs over the 4 threads sharing l, then one atomic per (i,l)
#pragma unroll
    for (int i = 0; i < HH; ++i) {
        float zr = zs[i];
        zr += __shfl_xor(zr, 1);
        zr += __shfl_xor(zr, 2);
        if ((tid & 3) == 0)
            atomicAdd(&z[(size_t)(b * HH + i) * LL + l0 + l], zr);
    }
}

// ---------------- pv_fused: P' = postmix(exp(S')/z); att = P' @ V ----------------
// Block: (l-tile 16, b). Double-buffered k-chunks of 32; all 12 i per block;
// waves split d (16 each). pp (P' relay) padded to 40 shorts/row.
__global__ __launch_bounds__(256) void pv_fused(const ushort_t* __restrict__ S,
                                                const ushort_t* __restrict__ Vt,
                                                const float* __restrict__ z,
                                                const float* __restrict__ Wpost,
                                                ushort_t* __restrict__ att) {
    __shared__ __align__(16) ushort_t sp[2][HH * 16 * 32];  // [i][l][k] 12 KB each
    __shared__ __align__(16) ushort_t vt[2][HH * 64 * 32];  // [i][d][k] 48 KB each
    __shared__ __align__(16) ushort_t pp[HH * 16 * 40];     // [i][l][k] padded, 15 KB

    const int tid = threadIdx.x;
    const int l0 = blockIdx.x * 16, b = blockIdx.y;
    const int wave = tid >> 6, lane = tid & 63;
    const int quad = lane >> 4, lq = lane & 15;
    const int co = (tid & 3) * 8, r0 = tid >> 2;
    const int la = tid >> 4, k2 = (tid & 15) * 2;

    // inverse softmax denominators for this block's 16 l-rows (per-thread for its la)
    float invr[HH];
#pragma unroll
    for (int h = 0; h < HH; ++h)
        invr[h] = 1.0f / z[(size_t)(b * HH + h) * LL + l0 + la];

    // stage chunk 0
#pragma unroll
    for (int s = 0; s < 3; ++s) {
        int row = r0 + 64 * s, i = row >> 4, l = row & 15;
        __builtin_amdgcn_global_load_lds(
            (const __attribute__((address_space(1))) void*)(S + ((size_t)(b * HH + i) * LL + l0 + l) * LL + co),
            (__attribute__((address_space(3))) void*)(sp[0] + row * 32 + co), 16, 0, 0);
    }
#pragma unroll
    for (int s = 0; s < 12; ++s) {
        int row = r0 + 64 * s, i = row >> 6, d = row & 63;
        __builtin_amdgcn_global_load_lds(
            (const __attribute__((address_space(1))) void*)(Vt + ((size_t)(b * HH + i) * DD + d) * LL + co),
            (__attribute__((address_space(3))) void*)(vt[0] + row * 32 + co), 16, 0, 0);
    }

    f32x4 acco[HH] = {};

    for (int n = 0; n < 32; ++n) {
        const int cur = n & 1, nxt = cur ^ 1;
        __syncthreads();   // dma(n) complete; pp reads of n-1 done

        // phase A: P'[i][la][k2..k2+1] = sum_h Wpost[h,i] * exp(S'[h])*invz[h]
        f32x2 pacc[HH];
#pragma unroll
        for (int i = 0; i < HH; ++i) pacc[i] = 0.f;
#pragma unroll
        for (int h = 0; h < HH; ++h) {
            unsigned raw = *(unsigned*)&sp[cur][h * 512 + la * 32 + k2];
            f32x2 e;
            e.x = __expf(u2f(raw << 16)) * invr[h];
            e.y = __expf(u2f(raw & 0xFFFF0000u)) * invr[h];
#pragma unroll
            for (int i = 0; i < HH; ++i)
                pacc[i] += e * Wpost[h * HH + i];   // uniform -> s_load
        }
#pragma unroll
        for (int i = 0; i < HH; ++i) {
            ushort_t u[2] = {f2bf(pacc[i].x), f2bf(pacc[i].y)};
            *(unsigned*)&pp[i * 640 + la * 40 + k2] = *(unsigned*)u;
        }
        __syncthreads();   // pp visible

        // prefetch chunk n+1 (overlaps phase B)
        if (n + 1 < 32) {
            int k0n = (n + 1) * 32;
#pragma unroll
            for (int s = 0; s < 3; ++s) {
                int row = r0 + 64 * s, i = row >> 4, l = row & 15;
                __builtin_amdgcn_global_load_lds(
                    (const __attribute__((address_space(1))) void*)(S + ((size_t)(b * HH + i) * LL + l0 + l) * LL + k0n + co),
                    (__attribute__((address_space(3))) void*)(sp[nxt] + row * 32 + co), 16, 0, 0);
            }
#pragma unroll
            for (int s = 0; s < 12; ++s) {
                int row = r0 + 64 * s, i = row >> 6, d = row & 63;
                __builtin_amdgcn_global_load_lds(
                    (const __attribute__((address_space(1))) void*)(Vt + ((size_t)(b * HH + i) * DD + d) * LL + k0n + co),
                    (__attribute__((address_space(3))) void*)(vt[nxt] + row * 32 + co), 16, 0, 0);
            }
        }

        // phase B: per wave, d-quarter; acc O[i] over k
#pragma unroll
        for (int i = 0; i < HH; ++i) {
            bf16x8 a  = *(bf16x8*)&pp[i * 640 + lq * 40 + quad * 8];
            bf16x8 bv = *(bf16x8*)&vt[cur][i * 2048 + (wave * 16 + lq) * 32 + quad * 8];
            acco[i] = __builtin_amdgcn_mfma_f32_16x16x32_bf16(a, bv, acco[i], 0, 0, 0);
        }
    }

    // epilogue: att[b, l, i*64 + d] bf16; D rows = l (quad*4+r), cols = d (wave*16+lq)
#pragma unroll
    for (int i = 0; i < HH; ++i)
#pragma unroll
        for (int r = 0; r < 4; ++r)
            att[((size_t)(b * LL) + l0 + quad * 4 + r) * CC + i * DD + wave * 16 + lq] = f2bf(acco[i][r]);
}

// ---------------- out = att @ Wout (MFMA, fp32 out). BM=128, BN=64 -> 384 blocks ----------------
__global__ __launch_bounds__(256) void out_gemm(const ushort_t* __restrict__ A,
                                                const ushort_t* __restrict__ Wt,
                                                float* __restrict__ out) {
    __shared__ __align__(16) ushort_t a_lds[128 * 32];
    __shared__ __align__(16) ushort_t b_lds[64 * 32];

    const int tid = threadIdx.x;
    const int bm = blockIdx.x * 128, bn = blockIdx.y * 64;
    const int wave = tid >> 6, lane = tid & 63;
    const int quad = lane >> 4, lq = lane & 15;
    const int wr = wave >> 1, wc = wave & 1;

    f32x4 acc[4][2] = {};

    for (int k0 = 0; k0 < CC; k0 += 32) {
        stage_rows(A + (size_t)bm * CC + k0, CC, a_lds, 8192, wave, lane);
        stage_rows(Wt + (size_t)bn * CC + k0, CC, b_lds, 4096, wave, lane);
        __syncthreads();
        bf16x8 af[4], bfr[2];
#pragma unroll
        for (int mi = 0; mi < 4; ++mi)
            af[mi] = *(bf16x8*)&a_lds[(wr * 64 + mi * 16 + lq) * 32 + quad * 8];
#pragma unroll
        for (int ni = 0; ni < 2; ++ni)
            bfr[ni] = *(bf16x8*)&b_lds[(wc * 32 + ni * 16 + lq) * 32 + quad * 8];
#pragma unroll
        for (int mi = 0; mi < 4; ++mi)
#pragma unroll
            for (int ni = 0; ni < 2; ++ni)
                acc[mi][ni] = __builtin_amdgcn_mfma_f32_16x16x32_bf16(af[mi], bfr[ni], acc[mi][ni], 0, 0, 0);
        __syncthreads();
    }

#pragma unroll
    for (int mi = 0; mi < 4; ++mi)
#pragma unroll
        for (int ni = 0; ni < 2; ++ni)
#pragma unroll
            for (int r = 0; r < 4; ++r) {
                int row = bm + wr * 64 + mi * 16 + quad * 4 + r;
                int col = bn + wc * 32 + ni * 16 + lq;
                out[(size_t)row * CC + col] = acc[mi][ni][r];
            }
}

// ---------------- Launch ----------------
extern "C" void kernel_launch(void* const* d_in, const int* in_sizes, int n_in,
                              void* d_out, int out_size, void* d_ws, size_t ws_size,
                              hipStream_t stream) {
    const float* inputs_q  = (const float*)d_in[0];
    const float* inputs_kv = (const float*)d_in[1];
    const float* Wq   = (const float*)d_in[2];
    const float* Wk   = (const float*)d_in[3];
    const float* Wv   = (const float*)d_in[4];
    const float* Wout = (const float*)d_in[5];
    const float* Wpre  = (const float*)d_in[6];
    const float* Wpost = (const float*)d_in[7];
    float* out = (float*)d_out;

    const size_t nS   = (size_t)BB * HH * LL * LL;
    const size_t nQKV = (size_t)BB * HH * LL * DD;
    const size_t nW   = (size_t)CC * CC;

    ushort_t* Sb   = (ushort_t*)d_ws;
    ushort_t* Qb   = Sb + nS;
    ushort_t* Kb   = Qb + nQKV;
    ushort_t* Vtb  = Kb + nQKV;
    ushort_t* attb = Vtb + nQKV;
    ushort_t* inq  = attb + nQKV;
    ushort_t* inkv = inq + nQKV;
    ushort_t* Wqt  = inkv + nQKV;
    ushort_t* Wkt  = Wqt + nW;
    ushort_t* Wvt  = Wkt + nW;
    ushort_t* Wot  = Wvt + nW;
    float*    zbuf = (float*)(Wot + nW);   // BB*HH*LL floats = 196 KB

    dim3 blk(256);

    hipMemsetAsync(zbuf, 0, (size_t)BB * HH * LL * sizeof(float), stream);
    prep<<<dim3(5376), blk, 0, stream>>>(inputs_q, inputs_kv, Wq, Wk, Wv, Wout,
                                         inq, inkv, Wqt, Wkt, Wvt, Wot);
    proj_gemm<<<dim3(32, 6, 3), blk, 0, stream>>>(inq, inkv, Wqt, Wkt, Wvt, Qb, Kb, Vtb);
    qk_premix<<<dim3(32, 16, BB), blk, 0, stream>>>(Qb, Kb, Wpre, Sb, zbuf);
    pv_fused<<<dim3(64, BB), blk, 0, stream>>>(Sb, Vtb, zbuf, Wpost, attb);
    out_gemm<<<dim3(32, 12), blk, 0, stream>>>(attb, Wot, out);
}

// Round 8
// 255.859 us; speedup vs baseline: 1.1134x; 1.1134x over previous
//
#include <hip/hip_runtime.h>

#define BB 4
#define LL 1024
#define CC 768
#define HH 12
#define DD 64

typedef unsigned short ushort_t;
typedef __attribute__((ext_vector_type(8))) short bf16x8;
typedef __attribute__((ext_vector_type(4))) float f32x4;
typedef __attribute__((ext_vector_type(2))) float f32x2;

__device__ inline ushort_t f2bf(float x) {
    union { float f; unsigned u; } v; v.f = x;
    unsigned r = (v.u + 0x7FFFu + ((v.u >> 16) & 1u)) >> 16;
    return (ushort_t)r;
}
__device__ inline float bf2f(ushort_t u) {
    union { unsigned u; float f; } v; v.u = ((unsigned)u) << 16;
    return v.f;
}
__device__ inline float u2f(unsigned u) {
    union { unsigned u; float f; } v; v.u = u;
    return v.f;
}

// Stage rows x 32 shorts from g (row stride `stride` shorts) into LDS,
// contiguous 64B rows, via async global->LDS (16B/lane, wave-uniform LDS base).
__device__ inline void stage_rows(const ushort_t* __restrict__ g, int stride,
                                  ushort_t* lds, int nbytes, int wave, int lane) {
    const int ko = (lane & 3) << 3;
    const int rsub = lane >> 2;
    for (int off = wave * 1024; off < nbytes; off += 4096) {
        int row = (off >> 6) + rsub;
        __builtin_amdgcn_global_load_lds(
            (const __attribute__((address_space(1))) void*)(g + (size_t)row * stride + ko),
            (__attribute__((address_space(3))) void*)(lds + (off >> 1)),
            16, 0, 0);
    }
}

// ---------------- prep: cast inputs + cast/transpose weights (one launch) ----------------
__global__ __launch_bounds__(256) void prep(const float* __restrict__ q, const float* __restrict__ kv,
                                            const float* __restrict__ w0, const float* __restrict__ w1,
                                            const float* __restrict__ w2, const float* __restrict__ w3,
                                            ushort_t* __restrict__ qo, ushort_t* __restrict__ kvo,
                                            ushort_t* __restrict__ o0, ushort_t* __restrict__ o1,
                                            ushort_t* __restrict__ o2, ushort_t* __restrict__ o3) {
    __shared__ float t[32][33];
    const int bx = blockIdx.x;
    if (bx < 3072) {
        const float* src = bx < 1536 ? q : kv;
        ushort_t* dst = bx < 1536 ? qo : kvo;
        int bb = bx < 1536 ? bx : bx - 1536;
        size_t i = ((size_t)bb * 256 + threadIdx.x) * 8;
        float4 a = *(const float4*)(src + i);
        float4 b = *(const float4*)(src + i + 4);
        ushort_t u[8] = {f2bf(a.x), f2bf(a.y), f2bf(a.z), f2bf(a.w),
                         f2bf(b.x), f2bf(b.y), f2bf(b.z), f2bf(b.w)};
        *(uint4*)(dst + i) = *(uint4*)u;
    } else {
        int w = bx - 3072;
        int z = w / 576, rem = w % 576;
        const float* W = z == 0 ? w0 : z == 1 ? w1 : z == 2 ? w2 : w3;
        ushort_t* Wt   = z == 0 ? o0 : z == 1 ? o1 : z == 2 ? o2 : o3;
        const int c = threadIdx.x & 31, r0 = threadIdx.x >> 5;
        const int kb = (rem / 24) * 32, nb = (rem % 24) * 32;
#pragma unroll
        for (int i = 0; i < 4; ++i)
            t[r0 + 8 * i][c] = W[(size_t)(kb + r0 + 8 * i) * CC + nb + c];
        __syncthreads();
#pragma unroll
        for (int i = 0; i < 4; ++i)
            Wt[(size_t)(nb + r0 + 8 * i) * CC + kb + c] = f2bf(t[c][r0 + 8 * i]);
    }
}

// ---------------- fused Q/K/V projection (MFMA bf16), z picks target ----------------
__global__ __launch_bounds__(256) void proj_gemm(const ushort_t* __restrict__ Aq,
                                                 const ushort_t* __restrict__ Akv,
                                                 const ushort_t* __restrict__ Wqt,
                                                 const ushort_t* __restrict__ Wkt,
                                                 const ushort_t* __restrict__ Wvt,
                                                 ushort_t* __restrict__ Qo,
                                                 ushort_t* __restrict__ Ko,
                                                 ushort_t* __restrict__ Vto) {
    const int z = blockIdx.z;
    const ushort_t* A  = (z == 0) ? Aq : Akv;
    const ushort_t* Wt = (z == 0) ? Wqt : (z == 1 ? Wkt : Wvt);

    __shared__ __align__(16) ushort_t a_lds[128 * 32];
    __shared__ __align__(16) ushort_t b_lds[128 * 32];

    const int tid = threadIdx.x;
    const int bm = blockIdx.x * 128, bn = blockIdx.y * 128;
    const int wave = tid >> 6, lane = tid & 63;
    const int quad = lane >> 4, lq = lane & 15;
    const int wr = wave >> 1, wc = wave & 1;

    f32x4 acc[4][4] = {};

    for (int k0 = 0; k0 < CC; k0 += 32) {
        stage_rows(A + (size_t)bm * CC + k0, CC, a_lds, 8192, wave, lane);
        stage_rows(Wt + (size_t)bn * CC + k0, CC, b_lds, 8192, wave, lane);
        __syncthreads();
        bf16x8 af[4], bfr[4];
#pragma unroll
        for (int mi = 0; mi < 4; ++mi)
            af[mi] = *(bf16x8*)&a_lds[(wr * 64 + mi * 16 + lq) * 32 + quad * 8];
#pragma unroll
        for (int ni = 0; ni < 4; ++ni)
            bfr[ni] = *(bf16x8*)&b_lds[(wc * 64 + ni * 16 + lq) * 32 + quad * 8];
#pragma unroll
        for (int mi = 0; mi < 4; ++mi)
#pragma unroll
            for (int ni = 0; ni < 4; ++ni)
                acc[mi][ni] = __builtin_amdgcn_mfma_f32_16x16x32_bf16(af[mi], bfr[ni], acc[mi][ni], 0, 0, 0);
        __syncthreads();
    }

    const float scale = (z == 0) ? 0.125f : 1.0f;
#pragma unroll
    for (int mi = 0; mi < 4; ++mi)
#pragma unroll
        for (int ni = 0; ni < 4; ++ni)
#pragma unroll
            for (int r = 0; r < 4; ++r) {
                int row = bm + wr * 64 + mi * 16 + quad * 4 + r;  // b*1024+l
                int col = bn + wc * 64 + ni * 16 + lq;            // h*64+d
                int b = row >> 10, l = row & 1023, h = col >> 6, d = col & 63;
                ushort_t v = f2bf(acc[mi][ni][r] * scale);
                if (z == 0)      Qo[((size_t)(b * HH + h) * LL + l) * DD + d] = v;
                else if (z == 1) Ko[((size_t)(b * HH + h) * LL + l) * DD + d] = v;
                else             Vto[((size_t)(b * HH + h) * DD + d) * LL + l] = v;
            }
}

// ---------------- qk_premix: S'[b,i,l,k] = premix(QK^T), single S write ----------------
// Block: (k-tile 32, l-tile 64, b). h-loop builds T[12][64][32] in LDS (fp32->bf16),
// then premix in-LDS, write S' bf16 once.
__global__ __launch_bounds__(256) void qk_premix(const ushort_t* __restrict__ Q,
                                                 const ushort_t* __restrict__ K,
                                                 const float* __restrict__ Wpre,
                                                 ushort_t* __restrict__ S) {
    __shared__ __align__(16) ushort_t qt[2][128 * 32];  // [dhalf*64+l][32]
    __shared__ __align__(16) ushort_t kt[2][64 * 32];   // [dhalf*32+k][32]
    __shared__ __align__(16) ushort_t T[HH * 64 * 32];  // [h][l][k] 48 KB

    const int tid = threadIdx.x;
    const int k0 = blockIdx.x * 32, l0 = blockIdx.y * 64, b = blockIdx.z;
    const int wave = tid >> 6, lane = tid & 63;
    const int quad = lane >> 4, lq = lane & 15;

    // prefetch h=0
    {
        const ushort_t* Qh = Q + ((size_t)(b * HH) * LL + l0) * DD;
        const ushort_t* Kh = K + ((size_t)(b * HH) * LL + k0) * DD;
        stage_rows(Qh,      DD, qt[0],        4096, wave, lane);
        stage_rows(Qh + 32, DD, qt[0] + 2048, 4096, wave, lane);
        stage_rows(Kh,      DD, kt[0],        2048, wave, lane);
        stage_rows(Kh + 32, DD, kt[0] + 1024, 2048, wave, lane);
    }

    for (int h = 0; h < HH; ++h) {
        const int cur = h & 1, nxt = cur ^ 1;
        __syncthreads();   // dma(h) complete; reads of buf nxt (from h-1) done
        if (h + 1 < HH) {
            const ushort_t* Qh = Q + ((size_t)(b * HH + h + 1) * LL + l0) * DD;
            const ushort_t* Kh = K + ((size_t)(b * HH + h + 1) * LL + k0) * DD;
            stage_rows(Qh,      DD, qt[nxt],        4096, wave, lane);
            stage_rows(Qh + 32, DD, qt[nxt] + 2048, 4096, wave, lane);
            stage_rows(Kh,      DD, kt[nxt],        2048, wave, lane);
            stage_rows(Kh + 32, DD, kt[nxt] + 1024, 2048, wave, lane);
        }
        f32x4 acc[2] = {};
#pragma unroll
        for (int ks = 0; ks < 2; ++ks) {
            bf16x8 af = *(bf16x8*)&qt[cur][(ks * 64 + wave * 16 + lq) * 32 + quad * 8];
#pragma unroll
            for (int nt = 0; nt < 2; ++nt) {
                bf16x8 bf = *(bf16x8*)&kt[cur][(ks * 32 + nt * 16 + lq) * 32 + quad * 8];
                acc[nt] = __builtin_amdgcn_mfma_f32_16x16x32_bf16(af, bf, acc[nt], 0, 0, 0);
            }
        }
#pragma unroll
        for (int nt = 0; nt < 2; ++nt)
#pragma unroll
            for (int r = 0; r < 4; ++r) {
                int l = wave * 16 + quad * 4 + r;
                T[(h * 64 + l) * 32 + nt * 16 + lq] = f2bf(acc[nt][r]);
            }
    }
    __syncthreads();

    // premix: thread owns (l = tid>>2, k8 = (tid&3)*8), 8 k-elems, all 12 i.
    const int l = tid >> 2, k8 = (tid & 3) * 8;
    f32x2 pa[HH][4];
#pragma unroll
    for (int i = 0; i < HH; ++i) { pa[i][0] = 0.f; pa[i][1] = 0.f; pa[i][2] = 0.f; pa[i][3] = 0.f; }
#pragma unroll
    for (int h = 0; h < HH; ++h) {
        uint4 raw = *(uint4*)&T[(h * 64 + l) * 32 + k8];
        f32x2 v[4];
        v[0].x = u2f(raw.x << 16); v[0].y = u2f(raw.x & 0xFFFF0000u);
        v[1].x = u2f(raw.y << 16); v[1].y = u2f(raw.y & 0xFFFF0000u);
        v[2].x = u2f(raw.z << 16); v[2].y = u2f(raw.z & 0xFFFF0000u);
        v[3].x = u2f(raw.w << 16); v[3].y = u2f(raw.w & 0xFFFF0000u);
#pragma unroll
        for (int i = 0; i < HH; ++i) {
            float w = Wpre[h * HH + i];   // uniform -> s_load
            pa[i][0] += v[0] * w; pa[i][1] += v[1] * w;
            pa[i][2] += v[2] * w; pa[i][3] += v[3] * w;
        }
    }

#pragma unroll
    for (int i = 0; i < HH; ++i) {
        ushort_t u[8];
#pragma unroll
        for (int j = 0; j < 4; ++j) {
            u[2 * j]     = f2bf(pa[i][j].x);
            u[2 * j + 1] = f2bf(pa[i][j].y);
        }
        *(uint4*)&S[((size_t)(b * HH + i) * LL + l0 + l) * LL + k0 + k8] = *(uint4*)u;
    }
}

// ---------------- post_mix: P = postmix(exp(S') / rowsum), in-place on S ----------------
// Block: (l-pair, b). Waves 0-1 own row l0, waves 2-3 own row l0+1.
// Thread owns 8 consecutive k (uint4) across all 12 heads.
__global__ __launch_bounds__(256) void post_mix(ushort_t* __restrict__ S,
                                                const float* __restrict__ Wpost) {
    __shared__ float red[4][HH];

    const int tid = threadIdx.x;
    const int wave = tid >> 6, lane = tid & 63;
    const int half = tid >> 7;        // 0/1 -> which l row
    const int t = tid & 127;          // 0..127 within row
    const int l = blockIdx.x * 2 + half;
    const int b = blockIdx.y;

    const size_t hstride = (size_t)LL * LL;
    const size_t base = ((size_t)(b * HH) * LL + l) * LL + t * 8;

    // load + exp + per-head partial sums
    f32x2 p[HH][4];
    float sm[HH];
#pragma unroll
    for (int h = 0; h < HH; ++h) {
        uint4 raw = *(const uint4*)&S[base + h * hstride];
        p[h][0].x = __expf(u2f(raw.x << 16)); p[h][0].y = __expf(u2f(raw.x & 0xFFFF0000u));
        p[h][1].x = __expf(u2f(raw.y << 16)); p[h][1].y = __expf(u2f(raw.y & 0xFFFF0000u));
        p[h][2].x = __expf(u2f(raw.z << 16)); p[h][2].y = __expf(u2f(raw.z & 0xFFFF0000u));
        p[h][3].x = __expf(u2f(raw.w << 16)); p[h][3].y = __expf(u2f(raw.w & 0xFFFF0000u));
        f32x2 t2 = (p[h][0] + p[h][1]) + (p[h][2] + p[h][3]);
        float ss = t2.x + t2.y;
#pragma unroll
        for (int off = 32; off; off >>= 1) ss += __shfl_xor(ss, off);
        sm[h] = ss;
    }
    if (lane == 0) {
#pragma unroll
        for (int h = 0; h < HH; ++h) red[wave][h] = sm[h];
    }
    __syncthreads();

    // combine two waves of this row; scale by 1/rowsum
#pragma unroll
    for (int h = 0; h < HH; ++h) {
        float tot = red[half * 2][h] + red[half * 2 + 1][h];
        float inv = 1.0f / tot;
        p[h][0] *= inv; p[h][1] *= inv; p[h][2] *= inv; p[h][3] *= inv;
    }

    // postmix one output head at a time, pack, store in place
#pragma unroll
    for (int i = 0; i < HH; ++i) {
        f32x2 a0 = 0.f, a1 = 0.f, a2 = 0.f, a3 = 0.f;
#pragma unroll
        for (int h = 0; h < HH; ++h) {
            float w = Wpost[h * HH + i];  // uniform -> s_load
            a0 += p[h][0] * w; a1 += p[h][1] * w;
            a2 += p[h][2] * w; a3 += p[h][3] * w;
        }
        ushort_t u[8] = {f2bf(a0.x), f2bf(a0.y), f2bf(a1.x), f2bf(a1.y),
                         f2bf(a2.x), f2bf(a2.y), f2bf(a3.x), f2bf(a3.y)};
        *(uint4*)&S[base + i * hstride] = *(uint4*)u;
    }
}

// ---------------- PV: BM=64, BN=64; att[b*L+l][h*64+d] bf16 ----------------
__global__ __launch_bounds__(256) void pv_gemm(const ushort_t* __restrict__ P,
                                               const ushort_t* __restrict__ Vt,
                                               ushort_t* __restrict__ att) {
    __shared__ __align__(16) ushort_t a_lds[64 * 32];
    __shared__ __align__(16) ushort_t b_lds[64 * 32];

    const int tid = threadIdx.x;
    const int bm = blockIdx.x * 64;
    const int bh = blockIdx.y;
    const int b = bh / HH, ih = bh % HH;
    const ushort_t* Ph = P + ((size_t)bh << 20);
    const ushort_t* Vh = Vt + (size_t)bh * LL * DD;
    const int wave = tid >> 6, lane = tid & 63;
    const int quad = lane >> 4, lq = lane & 15;
    const int wr = wave >> 1, wc = wave & 1;

    f32x4 acc[2][2] = {};

    for (int k0 = 0; k0 < LL; k0 += 32) {
        stage_rows(Ph + (size_t)bm * LL + k0, LL, a_lds, 4096, wave, lane);
        stage_rows(Vh + k0, LL, b_lds, 4096, wave, lane);
        __syncthreads();
        bf16x8 af[2], bfr[2];
#pragma unroll
        for (int mi = 0; mi < 2; ++mi)
            af[mi] = *(bf16x8*)&a_lds[(wr * 32 + mi * 16 + lq) * 32 + quad * 8];
#pragma unroll
        for (int ni = 0; ni < 2; ++ni)
            bfr[ni] = *(bf16x8*)&b_lds[(wc * 32 + ni * 16 + lq) * 32 + quad * 8];
#pragma unroll
        for (int mi = 0; mi < 2; ++mi)
#pragma unroll
            for (int ni = 0; ni < 2; ++ni)
                acc[mi][ni] = __builtin_amdgcn_mfma_f32_16x16x32_bf16(af[mi], bfr[ni], acc[mi][ni], 0, 0, 0);
        __syncthreads();
    }

#pragma unroll
    for (int mi = 0; mi < 2; ++mi)
#pragma unroll
        for (int ni = 0; ni < 2; ++ni)
#pragma unroll
            for (int r = 0; r < 4; ++r) {
                int lrow = bm + wr * 32 + mi * 16 + quad * 4 + r;
                int col = wc * 32 + ni * 16 + lq;  // d
                att[((size_t)(b * LL) + lrow) * CC + ih * DD + col] = f2bf(acc[mi][ni][r]);
            }
}

// ---------------- out = att @ Wout (MFMA, fp32 out). BM=128, BN=64 -> 384 blocks ----------------
__global__ __launch_bounds__(256) void out_gemm(const ushort_t* __restrict__ A,
                                                const ushort_t* __restrict__ Wt,
                                                float* __restrict__ out) {
    __shared__ __align__(16) ushort_t a_lds[128 * 32];
    __shared__ __align__(16) ushort_t b_lds[64 * 32];

    const int tid = threadIdx.x;
    const int bm = blockIdx.x * 128, bn = blockIdx.y * 64;
    const int wave = tid >> 6, lane = tid & 63;
    const int quad = lane >> 4, lq = lane & 15;
    const int wr = wave >> 1, wc = wave & 1;

    f32x4 acc[4][2] = {};

    for (int k0 = 0; k0 < CC; k0 += 32) {
        stage_rows(A + (size_t)bm * CC + k0, CC, a_lds, 8192, wave, lane);
        stage_rows(Wt + (size_t)bn * CC + k0, CC, b_lds, 4096, wave, lane);
        __syncthreads();
        bf16x8 af[4], bfr[2];
#pragma unroll
        for (int mi = 0; mi < 4; ++mi)
            af[mi] = *(bf16x8*)&a_lds[(wr * 64 + mi * 16 + lq) * 32 + quad * 8];
#pragma unroll
        for (int ni = 0; ni < 2; ++ni)
            bfr[ni] = *(bf16x8*)&b_lds[(wc * 32 + ni * 16 + lq) * 32 + quad * 8];
#pragma unroll
        for (int mi = 0; mi < 4; ++mi)
#pragma unroll
            for (int ni = 0; ni < 2; ++ni)
                acc[mi][ni] = __builtin_amdgcn_mfma_f32_16x16x32_bf16(af[mi], bfr[ni], acc[mi][ni], 0, 0, 0);
        __syncthreads();
    }

#pragma unroll
    for (int mi = 0; mi < 4; ++mi)
#pragma unroll
        for (int ni = 0; ni < 2; ++ni)
#pragma unroll
            for (int r = 0; r < 4; ++r) {
                int row = bm + wr * 64 + mi * 16 + quad * 4 + r;
                int col = bn + wc * 32 + ni * 16 + lq;
                out[(size_t)row * CC + col] = acc[mi][ni][r];
            }
}

// ---------------- Launch ----------------
extern "C" void kernel_launch(void* const* d_in, const int* in_sizes, int n_in,
                              void* d_out, int out_size, void* d_ws, size_t ws_size,
                              hipStream_t stream) {
    const float* inputs_q  = (const float*)d_in[0];
    const float* inputs_kv = (const float*)d_in[1];
    const float* Wq   = (const float*)d_in[2];
    const float* Wk   = (const float*)d_in[3];
    const float* Wv   = (const float*)d_in[4];
    const float* Wout = (const float*)d_in[5];
    const float* Wpre  = (const float*)d_in[6];
    const float* Wpost = (const float*)d_in[7];
    float* out = (float*)d_out;

    const size_t nS   = (size_t)BB * HH * LL * LL;
    const size_t nQKV = (size_t)BB * HH * LL * DD;
    const size_t nW   = (size_t)CC * CC;

    ushort_t* Sb   = (ushort_t*)d_ws;
    ushort_t* Qb   = Sb + nS;
    ushort_t* Kb   = Qb + nQKV;
    ushort_t* Vtb  = Kb + nQKV;
    ushort_t* attb = Vtb + nQKV;
    ushort_t* inq  = attb + nQKV;
    ushort_t* inkv = inq + nQKV;
    ushort_t* Wqt  = inkv + nQKV;
    ushort_t* Wkt  = Wqt + nW;
    ushort_t* Wvt  = Wkt + nW;
    ushort_t* Wot  = Wvt + nW;

    dim3 blk(256);

    prep<<<dim3(5376), blk, 0, stream>>>(inputs_q, inputs_kv, Wq, Wk, Wv, Wout,
                                         inq, inkv, Wqt, Wkt, Wvt, Wot);
    proj_gemm<<<dim3(32, 6, 3), blk, 0, stream>>>(inq, inkv, Wqt, Wkt, Wvt, Qb, Kb, Vtb);
    qk_premix<<<dim3(32, 16, BB), blk, 0, stream>>>(Qb, Kb, Wpre, Sb);
    post_mix<<<dim3(512, BB), blk, 0, stream>>>(Sb, Wpost);
    pv_gemm<<<dim3(16, BB * HH), blk, 0, stream>>>(Sb, Vtb, attb);
    out_gemm<<<dim3(32, 12), blk, 0, stream>>>(attb, Wot, out);
}